// Round 4
// baseline (1169.861 us; speedup 1.0000x reference)
//
#include <hip/hip_runtime.h>
#include <hip/hip_bf16.h>

#define N_ROWS 8192
#define DDIM 1024
#define HDIM 4096
#define ODIM 1024
#define NEXP 8
#define MAXT 72                 // max 256-row slot tiles: sum ceil(cnt_e/256) <= 71
#define MAXSLOTS (MAXT * 256)

// ws layout (bytes) — Wt shared by W1t then W2t (transposed sequentially)
#define O_XB      0ull
#define O_WT      16777216ull
#define O_H       83886080ull
#define O_ROWSPE  234881024ull
#define O_WPE     235143168ull
#define O_SROWS   235405312ull
#define O_SW      235479040ull
#define O_CNT     235552768ull
#define WS_NEEDED 235552800ull

typedef short bf16x8 __attribute__((ext_vector_type(8)));
typedef float f32x4 __attribute__((ext_vector_type(4)));

__device__ __forceinline__ unsigned short f2bf(float f) {
  unsigned u = __float_as_uint(f);
  u = (u + 0x7fffu + ((u >> 16) & 1u)) >> 16;
  return (unsigned short)u;
}

__device__ __forceinline__ void async_cp16(const void* g, void* l) {
  __builtin_amdgcn_global_load_lds(
      (const __attribute__((address_space(1))) unsigned int*)g,
      (__attribute__((address_space(3))) unsigned int*)l, 16, 0, 0);
}

// ---- per-expert [R,C] fp32 -> [C,R] bf16, vectorized ----
__global__ __launch_bounds__(256) void transpose_cvt_kernel(const float* __restrict__ in,
                                                            unsigned short* __restrict__ out,
                                                            int R, int C) {
  __shared__ float t[64][65];
  size_t ebase = (size_t)blockIdx.z * R * C;
  int r0 = blockIdx.x * 64, c0 = blockIdx.y * 64;
  int tid = threadIdx.x;
  int lr = tid >> 4, lc = (tid & 15) * 4;
#pragma unroll
  for (int i = 0; i < 4; i++) {
    int r = i * 16 + lr;
    float4 v = *(const float4*)(in + ebase + (size_t)(r0 + r) * C + (c0 + lc));
    t[r][lc] = v.x; t[r][lc + 1] = v.y; t[r][lc + 2] = v.z; t[r][lc + 3] = v.w;
  }
  __syncthreads();
#pragma unroll
  for (int j = 0; j < 2; j++) {
    int item = tid + j * 256;        // 512 items: 64 cols x 8 row-groups
    int c = item >> 3, r8 = (item & 7) * 8;
    union { unsigned short s[8]; uint4 v; } u;
#pragma unroll
    for (int rr = 0; rr < 8; rr++) u.s[rr] = f2bf(t[r8 + rr][c]);
    *(uint4*)(out + ebase + (size_t)(c0 + c) * R + (r0 + r8)) = u.v;
  }
}

// ---- gating (+ fused x->bf16 cvt): fp32 GEMV + softmax/T + top2 + renorm ----
__global__ __launch_bounds__(256) void gate_kernel(const float* __restrict__ x,
                                                   const float* __restrict__ Wg,
                                                   const float* __restrict__ bg,
                                                   int* __restrict__ cnt,
                                                   int* __restrict__ rowsPE,
                                                   float* __restrict__ wPE,
                                                   unsigned short* __restrict__ xb) {
  __shared__ float wgt[NEXP * DDIM];  // transposed [e][d]
  int tid = threadIdx.x;
  int row0 = blockIdx.x * 4;
  // fused x -> bf16 for this block's 4 rows (coalesced 16-B loads/stores)
  for (int i = tid; i < 512; i += 256) {
    size_t off = (size_t)row0 * DDIM + i * 8;
    float4 a = *(const float4*)(x + off);
    float4 b = *(const float4*)(x + off + 4);
    union { unsigned short s[8]; uint4 v; } u;
    u.s[0] = f2bf(a.x); u.s[1] = f2bf(a.y); u.s[2] = f2bf(a.z); u.s[3] = f2bf(a.w);
    u.s[4] = f2bf(b.x); u.s[5] = f2bf(b.y); u.s[6] = f2bf(b.z); u.s[7] = f2bf(b.w);
    *(uint4*)(xb + off) = u.v;
  }
  for (int i = tid; i < NEXP * DDIM; i += 256) {
    int d = i >> 3, e = i & 7;
    wgt[e * DDIM + d] = Wg[i];
  }
  __syncthreads();
  int lane = tid & 63;
  int row = row0 + (tid >> 6);
  const float* xr = x + (size_t)row * DDIM;
  float acc[NEXP];
#pragma unroll
  for (int e = 0; e < NEXP; e++) acc[e] = 0.f;
  for (int j = 0; j < DDIM / 64; j++) {
    int d = j * 64 + lane;
    float xv = xr[d];
#pragma unroll
    for (int e = 0; e < NEXP; e++) acc[e] += xv * wgt[e * DDIM + d];
  }
#pragma unroll
  for (int e = 0; e < NEXP; e++) {
#pragma unroll
    for (int off = 32; off > 0; off >>= 1) acc[e] += __shfl_xor(acc[e], off, 64);
  }
  if (lane == 0) {
    float s[NEXP], p[NEXP];
    float m = -1e30f;
#pragma unroll
    for (int e = 0; e < NEXP; e++) {
      s[e] = (acc[e] + bg[e]) * 0.36787944117144233f;  // 1/TEMP, TEMP=e
      m = s[e] > m ? s[e] : m;
    }
    float sum = 0.f;
#pragma unroll
    for (int e = 0; e < NEXP; e++) { p[e] = __expf(s[e] - m); sum += p[e]; }
    float inv = 1.0f / sum;
#pragma unroll
    for (int e = 0; e < NEXP; e++) p[e] *= inv;
    int i1 = 0;
#pragma unroll
    for (int e = 1; e < NEXP; e++) if (p[e] > p[i1]) i1 = e;
    int i2 = (i1 == 0) ? 1 : 0;
#pragma unroll
    for (int e = 0; e < NEXP; e++) if (e != i1 && p[e] > p[i2]) i2 = e;
    float denom = p[i1] + p[i2] + 1e-8f;
    float w1 = p[i1] / denom, w2 = p[i2] / denom;
    int pos1 = atomicAdd(&cnt[i1], 1);
    rowsPE[i1 * N_ROWS + pos1] = row; wPE[i1 * N_ROWS + pos1] = w1;
    int pos2 = atomicAdd(&cnt[i2], 1);
    rowsPE[i2 * N_ROWS + pos2] = row; wPE[i2 * N_ROWS + pos2] = w2;
  }
}

// ---- compact per-expert lists into 256-padded slot arrays (prefix from cnt) ----
__global__ __launch_bounds__(256) void scatter_kernel(const int* __restrict__ cnt,
                                                      const int* __restrict__ rowsPE,
                                                      const float* __restrict__ wPE,
                                                      int* __restrict__ srows,
                                                      float* __restrict__ sw) {
  int e = blockIdx.x;
  int a0 = 0;
  for (int j = 0; j < e; j++) a0 += ((cnt[j] + 255) >> 8) << 8;
  int c = cnt[e];
  int padded = ((c + 255) >> 8) << 8;
  for (int i = threadIdx.x; i < padded; i += 256) {
    if (i < c) { srows[a0 + i] = rowsPE[e * N_ROWS + i]; sw[a0 + i] = wPE[e * N_ROWS + i]; }
    else       { srows[a0 + i] = 0;                      sw[a0 + i] = 0.f; }
  }
}

// ---- grouped GEMM: 256x256 tile, 8 waves (512 thr), 16x16x32 bf16 MFMA ----
// Double-buffered async LDS staging (64 KB). Each wave: 64 rows x 128 cols
// (acc[4][8]). Group-swizzled raster (GM tiles share B K-slices). Optional
// split-K (atomic fp32 epilogue; bias applied only by ks==0).
template <bool GATHER, bool RELU, int GM>
__global__ __launch_bounds__(512, 2) void gemm_kernel(
    const unsigned short* __restrict__ A, const unsigned short* __restrict__ Bt,
    const float* __restrict__ bias, unsigned short* __restrict__ Hout,
    float* __restrict__ Out, const int* __restrict__ srows, const float* __restrict__ sw,
    const int* __restrict__ cnt, int KFULL, int klen, int NDIM, int nty, int nsplit) {
  __shared__ unsigned short lds[32768];  // 2 bufs x (A 256x32 @0 | B 256x32 @8192) ushorts
  int b = blockIdx.x;
  int perx = nty * nsplit;
  int perg = GM * perx;
  int g = b / perg, r = b - g * perg;
  int xt = g * GM + (r % GM);
  int q = r / GM;
  int yt = q % nty;
  int ks = q / nty;
  // prefix over cnt: find expert + slot base for this M-tile
  int e = -1, slot0 = 0;
  {
    int t = 0, a = 0;
    for (int j = 0; j < NEXP; j++) {
      int tiles = (cnt[j] + 255) >> 8;
      if (e < 0 && xt < t + tiles) { e = j; slot0 = a + ((xt - t) << 8); }
      t += tiles; a += tiles << 8;
    }
  }
  if (e < 0) return;
  int n0 = yt << 8;
  int kbase = ks * klen;
  const unsigned short* Bte = Bt + (size_t)e * NDIM * KFULL;

  int tid = threadIdx.x, wave = tid >> 6, lane = tid & 63;
  // staging: each wave stages 32 A-rows + 32 B-rows (2 issues of 16 rows each).
  // XOR swizzle folded into global addr (LDS dest is wave-uniform base + lane*16B).
  int ri = lane >> 2, cs = lane & 3;
  int kchunk = cs ^ ((ri & 3) ^ (ri >> 2));
  const unsigned short* aptr[2];
  const unsigned short* bptr[2];
#pragma unroll
  for (int j = 0; j < 2; j++) {
    int rt = wave * 32 + j * 16 + ri;
    int arow = GATHER ? srows[slot0 + rt] : (slot0 + rt);
    aptr[j] = A + (size_t)arow * KFULL + kbase + kchunk * 8;
    bptr[j] = Bte + (size_t)(n0 + rt) * KFULL + kbase + kchunk * 8;
  }

  // fragment read offsets (swizzle-aware)
  int l4 = lane & 15, quad = lane >> 4;
  int rchunk = quad ^ ((l4 & 3) ^ (l4 >> 2));
  int wm = wave >> 1, wn = wave & 1;  // 4 row-strips x 2 col-strips
  int aoffs[4], boffs[8];
#pragma unroll
  for (int i = 0; i < 4; i++) aoffs[i] = (wm * 64 + i * 16 + l4) * 32 + rchunk * 8;
#pragma unroll
  for (int i = 0; i < 8; i++) boffs[i] = 8192 + (wn * 128 + i * 16 + l4) * 32 + rchunk * 8;

  f32x4 zero = {0.f, 0.f, 0.f, 0.f};
  f32x4 acc[4][8];
#pragma unroll
  for (int mi = 0; mi < 4; mi++)
#pragma unroll
    for (int ni = 0; ni < 8; ni++) acc[mi][ni] = zero;

  // prologue: stage k-chunk 0 into buffer 0
  {
    unsigned short* la = &lds[wave * 1024];
    unsigned short* lb = &lds[8192 + wave * 1024];
#pragma unroll
    for (int j = 0; j < 2; j++) {
      async_cp16(aptr[j], la + j * 512);
      async_cp16(bptr[j], lb + j * 512);
    }
  }

  int it = 0;
  for (int k0 = 0; k0 < klen; k0 += 32, it ^= 1) {
    __syncthreads();  // buffer `it` staged; prior reads of `it^1` done
    if (k0 + 32 < klen) {
      int nb = (it ^ 1) * 16384;
      unsigned short* la = &lds[nb + wave * 1024];
      unsigned short* lb = &lds[nb + 8192 + wave * 1024];
#pragma unroll
      for (int j = 0; j < 2; j++) {
        async_cp16(aptr[j] + k0 + 32, la + j * 512);
        async_cp16(bptr[j] + k0 + 32, lb + j * 512);
      }
    }
    int base = it * 16384;
    bf16x8 af[4], bfr[8];
#pragma unroll
    for (int i = 0; i < 4; i++) af[i] = *(const bf16x8*)&lds[base + aoffs[i]];
#pragma unroll
    for (int i = 0; i < 8; i++) bfr[i] = *(const bf16x8*)&lds[base + boffs[i]];
#pragma unroll
    for (int mi = 0; mi < 4; mi++)
#pragma unroll
      for (int ni = 0; ni < 8; ni++)
        acc[mi][ni] = __builtin_amdgcn_mfma_f32_16x16x32_bf16(af[mi], bfr[ni], acc[mi][ni], 0, 0, 0);
  }

  // epilogue
  float bvs[8];
#pragma unroll
  for (int ni = 0; ni < 8; ni++) {
    int col = n0 + wn * 128 + ni * 16 + l4;
    bvs[ni] = (RELU || ks == 0) ? bias[e * NDIM + col] : 0.f;
  }
#pragma unroll
  for (int mi = 0; mi < 4; mi++) {
#pragma unroll
    for (int r2 = 0; r2 < 4; r2++) {
      int srow = slot0 + wm * 64 + mi * 16 + quad * 4 + r2;
      if (RELU) {
        unsigned short* hrow = Hout + (size_t)srow * NDIM + n0 + wn * 128 + l4;
#pragma unroll
        for (int ni = 0; ni < 8; ni++) {
          float v = acc[mi][ni][r2] + bvs[ni];
          hrow[ni * 16] = f2bf(v > 0.f ? v : 0.f);
        }
      } else {
        int orow = srows[srow];
        float w = sw[srow];
        float* orp = Out + (size_t)orow * ODIM + n0 + wn * 128 + l4;
#pragma unroll
        for (int ni = 0; ni < 8; ni++)
          atomicAdd(orp + ni * 16, w * (acc[mi][ni][r2] + bvs[ni]));
      }
    }
  }
}

extern "C" void kernel_launch(void* const* d_in, const int* in_sizes, int n_in,
                              void* d_out, int out_size, void* d_ws, size_t ws_size,
                              hipStream_t stream) {
  const float* x  = (const float*)d_in[0];
  const float* Wg = (const float*)d_in[1];
  const float* bg = (const float*)d_in[2];
  const float* W1 = (const float*)d_in[3];
  const float* b1 = (const float*)d_in[4];
  const float* W2 = (const float*)d_in[5];
  const float* b2 = (const float*)d_in[6];
  float* out = (float*)d_out;

  char* ws = (char*)d_ws;
  unsigned short* xb   = (unsigned short*)(ws + O_XB);
  unsigned short* Wt   = (unsigned short*)(ws + O_WT);
  unsigned short* hbuf = (unsigned short*)(ws + O_H);
  int*   rowsPE = (int*)(ws + O_ROWSPE);
  float* wPE    = (float*)(ws + O_WPE);
  int*   srows  = (int*)(ws + O_SROWS);
  float* swt    = (float*)(ws + O_SW);
  int*   cnt    = (int*)(ws + O_CNT);

  hipMemsetAsync(d_out, 0, (size_t)N_ROWS * ODIM * sizeof(float), stream);
  if (ws_size < WS_NEEDED) return;  // loud fail: output stays zero
  hipMemsetAsync(cnt, 0, NEXP * sizeof(int), stream);

  gate_kernel<<<dim3(N_ROWS / 4), 256, 0, stream>>>(x, Wg, bg, cnt, rowsPE, wPE, xb);
  transpose_cvt_kernel<<<dim3(DDIM / 64, HDIM / 64, NEXP), 256, 0, stream>>>(W1, Wt, DDIM, HDIM);
  scatter_kernel<<<dim3(NEXP), 256, 0, stream>>>(cnt, rowsPE, wPE, srows, swt);
  // GEMM1: A=xb gathered, B=W1t, K=1024, N=4096, no split
  gemm_kernel<true, true, 8><<<dim3((MAXT / 8) * 8 * (HDIM / 256) * 1), 512, 0, stream>>>(
      xb, Wt, b1, hbuf, nullptr, srows, swt, cnt, DDIM, DDIM, HDIM, HDIM / 256, 1);
  // W2 transpose reuses Wt (W1t dead after GEMM1)
  transpose_cvt_kernel<<<dim3(HDIM / 64, ODIM / 64, NEXP), 256, 0, stream>>>(W2, Wt, HDIM, ODIM);
  // GEMM2: A=hbuf direct, B=W2t, K=4096 split 2x2048, N=1024, atomic epilogue
  gemm_kernel<false, false, 8><<<dim3((MAXT / 8) * 8 * (ODIM / 256) * 2), 512, 0, stream>>>(
      hbuf, Wt, b2, nullptr, out, srows, swt, cnt, HDIM, HDIM / 2, ODIM, ODIM / 256, 2);
}